// Round 9
// baseline (253.465 us; speedup 1.0000x reference)
//
#include <hip/hip_runtime.h>
#include <math.h>

// OfflinePrepareLayer: N=200000 nodes, E=6400000 edges, ENV=3, HIST=15, R=0.05
// d_out (f32, concat): node_feature (N,21) | edge_feature (E,4) | current_v (N,3)
//
// Model from rounds 4+7: edge path is VMEM-issue bound (~1.1 cyc per VMEM
// instruction per lane of work). Minimize VMEM instructions per edge:
//   pre-pass packs pos (12B rows) -> pos4 (16B rows) in d_ws, so each
//   endpoint gather is ONE aligned dwordx4. 2 gathers + 0.5 idx + 1 store
//   = 3.5 VMEM/edge (was ~6-9). Edge stores are normal (not nt): round-7
//   showed nt + 4-consecutive-per-thread partial-line evicts -> 187MB writes.

static constexpr float INV_R = 20.0f;   // 1/0.05

typedef float f32x4 __attribute__((ext_vector_type(4)));
typedef int   i32x4 __attribute__((ext_vector_type(4)));

// ---- pre-pass: pos (N,3) -> pos4 (N,4) in workspace ----
__global__ __launch_bounds__(256) void pack_pos_kernel(
    const float* __restrict__ pos, f32x4* __restrict__ pos4, int n)
{
    const int i = blockIdx.x * blockDim.x + threadIdx.x;
    if (i < n) {
        const float x = pos[3 * i + 0];
        const float y = pos[3 * i + 1];
        const float z = pos[3 * i + 2];
        f32x4 p = {x, y, z, 0.0f};
        pos4[i] = p;
    }
}

__global__ __launch_bounds__(256) void fused_kernel(
    const f32x4* __restrict__ pos4,     // (N,) packed, 16B rows
    const float* __restrict__ pos,      // (N,3) original (node path)
    const float* __restrict__ hist_v,   // (N,15)
    const float* __restrict__ bnd,      // (6,)
    const i32x4* __restrict__ src4,     // (E/4,)
    const i32x4* __restrict__ dst4,     // (E/4,)
    float* __restrict__ node_feat,      // (N,21)
    f32x4* __restrict__ edge_feat,      // (E,) 16B-aligned
    float* __restrict__ cur_v,          // (N,3)
    int n, int e4, int node_blocks)
{
    if ((int)blockIdx.x < node_blocks) {
        // ---- node work: grid-stride, fully coalesced ----
        const int stride = node_blocks * blockDim.x;
        const int tid = blockIdx.x * blockDim.x + threadIdx.x;

        const int total_nf = n * 21;
        for (int idx = tid; idx < total_nf; idx += stride) {
            const int node = idx / 21;
            const int c = idx - node * 21;
            float v;
            if (c < 15) {
                v = hist_v[node * 15 + c];
            } else {
                const int j = c - 15;
                const float p = pos[node * 3 + (j >> 1)];
                v = (p - bnd[j]) * INV_R;
                v = fminf(1.0f, fmaxf(-1.0f, v));
            }
            node_feat[idx] = v;
        }

        const int total_cv = n * 3;
        for (int idx = tid; idx < total_cv; idx += stride) {
            const int node = idx / 3;
            const int c = idx - node * 3;
            cur_v[idx] = hist_v[node * 15 + c];
        }
    } else {
        // ---- edge work: 4 edges/thread, 3.5 VMEM per edge ----
        const int t = (blockIdx.x - node_blocks) * blockDim.x + threadIdx.x;
        if (t >= e4) return;

        const i32x4 s4 = src4[t];   // coalesced dwordx4
        const i32x4 d4 = dst4[t];

        f32x4 ps[4], pd[4];
#pragma unroll
        for (int k = 0; k < 4; ++k) {
            ps[k] = pos4[s4[k]];    // one aligned dwordx4 gather each
            pd[k] = pos4[d4[k]];
        }
#pragma unroll
        for (int k = 0; k < 4; ++k) {
            const float rx = (ps[k].x - pd[k].x) * INV_R;
            const float ry = (ps[k].y - pd[k].y) * INV_R;
            const float rz = (ps[k].z - pd[k].z) * INV_R;
            const float dis = sqrtf(rx * rx + ry * ry + rz * rz);
            f32x4 o = {rx, ry, rz, dis};
            edge_feat[4 * t + k] = o;   // normal store: L2 merges 4x16B -> 1 line
        }
    }
}

extern "C" void kernel_launch(void* const* d_in, const int* in_sizes, int n_in,
                              void* d_out, int out_size, void* d_ws, size_t ws_size,
                              hipStream_t stream) {
    const float* pos    = (const float*)d_in[0];   // (N,3)
    const float* hist_v = (const float*)d_in[1];   // (N,15)
    const float* bnd    = (const float*)d_in[2];   // (6,)
    const int*   src    = (const int*)d_in[3];     // (E,)
    const int*   dst    = (const int*)d_in[4];     // (E,)

    const int N = in_sizes[0] / 3;
    const int E = in_sizes[3];
    const int e4 = E / 4;                          // E divisible by 4

    float* out       = (float*)d_out;
    float* node_feat = out;                                   // N*21
    float* edge_feat = out + (size_t)N * 21;                  // E*4; byte off N*84 % 16 == 0
    float* cur_v     = out + (size_t)N * 21 + (size_t)E * 4;  // N*3

    f32x4* pos4 = (f32x4*)d_ws;                    // N*16 B = 3.2 MB scratch

    const int block = 256;

    pack_pos_kernel<<<(N + block - 1) / block, block, 0, stream>>>(pos, pos4, N);

    const int node_blocks = 1024;
    const int edge_blocks = (e4 + block - 1) / block;   // 6250 at E=6.4M

    fused_kernel<<<node_blocks + edge_blocks, block, 0, stream>>>(
        pos4, pos, hist_v, bnd, (const i32x4*)src, (const i32x4*)dst,
        node_feat, (f32x4*)edge_feat, cur_v, N, e4, node_blocks);
}

// Round 10
// 239.888 us; speedup vs baseline: 1.0566x; 1.0566x over previous
//
#include <hip/hip_runtime.h>
#include <math.h>

// OfflinePrepareLayer: N=200000 nodes, E=6400000 edges, ENV=3, HIST=15, R=0.05
// d_out (f32, concat): node_feature (N,21) | edge_feature (E,4) | current_v (N,3)
//
// Model (rounds 4/7/9): edge path is bound by divergent lane-gathers
// (~4.2 cyc each when pos falls out of L2). Strategy: pos4 (16B rows, d_ws)
// is the ONLY L2-allocating traffic — all streaming reads (src/dst/hist_v)
// and all stores are nontemporal. Edge work is wave-strided (k*256) so every
// nt store instruction covers contiguous full lines (round-7's 187MB
// write-amplification came from nt + per-thread-consecutive stores).

static constexpr float INV_R = 20.0f;   // 1/0.05

typedef float f32x4 __attribute__((ext_vector_type(4)));

// ---- pre-pass: pos (N,3) -> pos4 (N,4) in workspace ----
__global__ __launch_bounds__(256) void pack_pos_kernel(
    const float* __restrict__ pos, f32x4* __restrict__ pos4, int n)
{
    const int i = blockIdx.x * blockDim.x + threadIdx.x;
    if (i < n) {
        f32x4 p = {pos[3 * i + 0], pos[3 * i + 1], pos[3 * i + 2], 0.0f};
        pos4[i] = p;
    }
}

__global__ __launch_bounds__(256) void fused_kernel(
    const f32x4* __restrict__ pos4,     // (N,) packed 16B rows — L2-resident
    const float* __restrict__ pos,      // (N,3) original (node path, tiny)
    const float* __restrict__ hist_v,   // (N,15) streaming
    const float* __restrict__ bnd,      // (6,)
    const int*   __restrict__ src,      // (E,) streaming
    const int*   __restrict__ dst,      // (E,) streaming
    float* __restrict__ node_feat,      // (N,21)
    f32x4* __restrict__ edge_feat,      // (E,) 16B-aligned
    float* __restrict__ cur_v,          // (N,3)
    int n, int e, int node_blocks)
{
    if ((int)blockIdx.x < node_blocks) {
        // ---- node work: grid-stride, coalesced; nt so L2 stays pos4's ----
        const int stride = node_blocks * blockDim.x;
        const int tid = blockIdx.x * blockDim.x + threadIdx.x;

        const int total_nf = n * 21;
        for (int idx = tid; idx < total_nf; idx += stride) {
            const int node = idx / 21;
            const int c = idx - node * 21;
            float v;
            if (c < 15) {
                v = __builtin_nontemporal_load(&hist_v[node * 15 + c]);
            } else {
                const int j = c - 15;
                const float p = pos[node * 3 + (j >> 1)];
                v = (p - bnd[j]) * INV_R;
                v = fminf(1.0f, fmaxf(-1.0f, v));
            }
            __builtin_nontemporal_store(v, &node_feat[idx]);
        }

        const int total_cv = n * 3;
        for (int idx = tid; idx < total_cv; idx += stride) {
            const int node = idx / 3;
            const int c = idx - node * 3;
            const float v = __builtin_nontemporal_load(&hist_v[node * 15 + c]);
            __builtin_nontemporal_store(v, &cur_v[idx]);
        }
    } else {
        // ---- edge work: 1024-edge block, 4 edges/thread strided by 256.
        // Each nt store instruction: 64 lanes x 16B contiguous = full lines.
        const int base = (blockIdx.x - node_blocks) * 1024 + threadIdx.x;

        int sidx[4], didx[4];
#pragma unroll
        for (int k = 0; k < 4; ++k) {
            const int ei = base + k * 256;
            const bool ok = ei < e;
            sidx[k] = ok ? __builtin_nontemporal_load(&src[ei]) : 0;
            didx[k] = ok ? __builtin_nontemporal_load(&dst[ei]) : 0;
        }

        // 8 independent dwordx4 gathers in flight (L2-resident pos4)
        f32x4 ps[4], pd[4];
#pragma unroll
        for (int k = 0; k < 4; ++k) {
            ps[k] = pos4[sidx[k]];
            pd[k] = pos4[didx[k]];
        }

#pragma unroll
        for (int k = 0; k < 4; ++k) {
            const int ei = base + k * 256;
            if (ei < e) {
                const float rx = (ps[k].x - pd[k].x) * INV_R;
                const float ry = (ps[k].y - pd[k].y) * INV_R;
                const float rz = (ps[k].z - pd[k].z) * INV_R;
                const float dis = sqrtf(rx * rx + ry * ry + rz * rz);
                f32x4 o = {rx, ry, rz, dis};
                __builtin_nontemporal_store(o, &edge_feat[ei]);
            }
        }
    }
}

extern "C" void kernel_launch(void* const* d_in, const int* in_sizes, int n_in,
                              void* d_out, int out_size, void* d_ws, size_t ws_size,
                              hipStream_t stream) {
    const float* pos    = (const float*)d_in[0];   // (N,3)
    const float* hist_v = (const float*)d_in[1];   // (N,15)
    const float* bnd    = (const float*)d_in[2];   // (6,)
    const int*   src    = (const int*)d_in[3];     // (E,)
    const int*   dst    = (const int*)d_in[4];     // (E,)

    const int N = in_sizes[0] / 3;
    const int E = in_sizes[3];

    float* out       = (float*)d_out;
    float* node_feat = out;                                   // N*21
    float* edge_feat = out + (size_t)N * 21;                  // E*4; byte off N*84 % 16 == 0
    float* cur_v     = out + (size_t)N * 21 + (size_t)E * 4;  // N*3

    f32x4* pos4 = (f32x4*)d_ws;                    // N*16 B = 3.2 MB scratch

    const int block = 256;

    pack_pos_kernel<<<(N + block - 1) / block, block, 0, stream>>>(pos, pos4, N);

    const int node_blocks = 1024;
    const int edge_blocks = (E + 1023) / 1024;     // 6250 at E=6.4M

    fused_kernel<<<node_blocks + edge_blocks, block, 0, stream>>>(
        pos4, pos, hist_v, bnd, src, dst,
        node_feat, (f32x4*)edge_feat, cur_v, N, E, node_blocks);
}